// Round 5
// baseline (2343.918 us; speedup 1.0000x reference)
//
#include <hip/hip_runtime.h>
#include <stdint.h>

// ---------------- common types / helpers ----------------
typedef unsigned short u16;
typedef short s16x8 __attribute__((ext_vector_type(8)));
typedef unsigned short u16x4 __attribute__((ext_vector_type(4)));
typedef float f32x4 __attribute__((ext_vector_type(4)));

#define DEV static __device__ __forceinline__

DEV u16 f2b(float f) {
  union { float f; unsigned u; } v; v.f = f;
  unsigned r = v.u + 0x7fffu + ((v.u >> 16) & 1u);
  return (u16)(r >> 16);
}
DEV float b2f(u16 b) {
  union { unsigned u; float f; } v; v.u = ((unsigned)b) << 16; return v.f;
}
DEV f32x4 MFMA16(s16x8 a, s16x8 b, f32x4 c) {
  return __builtin_amdgcn_mfma_f32_16x16x32_bf16(a, b, c, 0, 0, 0);
}
#define GLD_LDS16(gp, lp)                                                            \
  __builtin_amdgcn_global_load_lds((const __attribute__((address_space(1))) void*)(gp), \
                                   (__attribute__((address_space(3))) void*)(lp), 16, 0, 0)

// dims: B=4 T=2048 M=2048 K=4096 D=1024 H=16 DH=64 FFN=4096

// ---------------- weight cast + transpose: Wt[n,k] = bf16(W[k,n]) ----------------
__global__ __launch_bounds__(256) void wt_cast_t(const float* __restrict__ W,
                                                 u16* __restrict__ Wt, int Kd, int Nd) {
  __shared__ float tile[32][33];
  const int n0 = blockIdx.x * 32, k0 = blockIdx.y * 32;
  const int t = threadIdx.x;
#pragma unroll
  for (int p = 0; p < 4; ++p) {
    int idx = p * 256 + t; int r = idx >> 5, c = idx & 31;
    tile[r][c] = W[(long)(k0 + r) * Nd + n0 + c];
  }
  __syncthreads();
#pragma unroll
  for (int p = 0; p < 4; ++p) {
    int idx = p * 256 + t; int r = idx >> 5, c = idx & 31;
    Wt[(long)(n0 + r) * Kd + k0 + c] = f2b(tile[c][r]);
  }
}

// ---------------- cb = bf16(concat(mem, x)) : [B,4096,1024] ----------------
__global__ __launch_bounds__(256) void build_cb(const float* __restrict__ x,
                                                const float* __restrict__ mem,
                                                u16* __restrict__ cb) {
  long idx = (long)blockIdx.x * 256 + threadIdx.x;  // one per 4 elems
  long e4 = idx * 4;
  int b = (int)(e4 >> 22);
  long rem = e4 & ((1L << 22) - 1);
  int tok = (int)(rem >> 10);
  int d = (int)(rem & 1023);
  const float* src = (tok < 2048) ? &mem[((long)b * 2048 + tok) * 1024 + d]
                                  : &x[((long)b * 2048 + (tok - 2048)) * 1024 + d];
  float4 vv = *(const float4*)src;
  uint2 o;
  o.x = (unsigned)f2b(vv.x) | ((unsigned)f2b(vv.y) << 16);
  o.y = (unsigned)f2b(vv.z) | ((unsigned)f2b(vv.w) << 16);
  *(uint2*)&cb[e4] = o;
}

// ---------------- pe[d, e] distance-indexed sinusoid table (bf16) ----------------
__global__ __launch_bounds__(256) void pos_emb(u16* __restrict__ pe) {
  const int d = blockIdx.x;          // 0..4095 (relative distance)
  const int e0 = threadIdx.x * 4;
  u16 o[4];
#pragma unroll
  for (int i = 0; i < 4; ++i) {
    int e = e0 + i;
    int f = (e < 512) ? e : (e - 512);
    float invf = expf(-(float)f * (9.210340371976184f / 512.f));  // 10000^(-f/512)
    float ang = (float)d * invf;
    o[i] = f2b((e < 512) ? sinf(ang) : cosf(ang));
  }
  uint2 pk; pk.x = (unsigned)o[0] | ((unsigned)o[1] << 16);
  pk.y = (unsigned)o[2] | ((unsigned)o[3] << 16);
  *(uint2*)&pe[(long)d * 1024 + e0] = pk;
}

// ---------------- GEMM: C[M,N] = A[M,K](bf16) @ Bt[N,K](bf16)^T + bias ----------------
#define EPI_BF16 0
#define EPI_F32 1
#define EPI_GELU 2
#define EPI_VT 3

template <int EPI, int QMAP>
__global__ __launch_bounds__(256) void gemm_bt(const u16* __restrict__ A,
                                               const u16* __restrict__ Bt,
                                               const float* __restrict__ bias,
                                               void* __restrict__ outp, int Ndim, int Kdim) {
  __shared__ __align__(16) u16 As[128 * 32];
  __shared__ __align__(16) u16 Bs[128 * 32];
  const int col0 = blockIdx.x * 128;
  const int row0 = blockIdx.y * 128;
  const int t = threadIdx.x;
  const int w = t >> 6, l = t & 63;
  const int wr = (w >> 1) * 64, wc = (w & 1) * 64;
  const int lr = l & 15, lk = (l >> 4) * 8;
  f32x4 acc[4][4];
#pragma unroll
  for (int m = 0; m < 4; ++m)
#pragma unroll
    for (int n = 0; n < 4; ++n) acc[m][n] = f32x4{0.f, 0.f, 0.f, 0.f};

  for (int k0 = 0; k0 < Kdim; k0 += 32) {
#pragma unroll
    for (int it = 0; it < 2; ++it) {
      int c = it * 256 + t;
      int r = c >> 2, e = (c & 3) * 8;
      long ga = row0 + r;
      if (QMAP) ga = ((ga >> 11) << 12) + 2048 + (ga & 2047);  // q rows live in cb at b*4096+2048+i
      GLD_LDS16(A + ga * Kdim + k0 + e, &As[c * 8]);
      GLD_LDS16(Bt + (long)(col0 + r) * Kdim + k0 + e, &Bs[c * 8]);
    }
    __syncthreads();
    s16x8 af[4], bfv[4];
#pragma unroll
    for (int m = 0; m < 4; ++m) af[m] = *(const s16x8*)&As[(wr + m * 16 + lr) * 32 + lk];
#pragma unroll
    for (int n = 0; n < 4; ++n) bfv[n] = *(const s16x8*)&Bs[(wc + n * 16 + lr) * 32 + lk];
#pragma unroll
    for (int m = 0; m < 4; ++m)
#pragma unroll
      for (int n = 0; n < 4; ++n) acc[m][n] = MFMA16(af[m], bfv[n], acc[m][n]);
    __syncthreads();
  }

  const int lg = (l >> 4) * 4;
#pragma unroll
  for (int m = 0; m < 4; ++m) {
    int rbase = row0 + wr + m * 16 + lg;
#pragma unroll
    for (int n = 0; n < 4; ++n) {
      int gc = col0 + wc + n * 16 + lr;
      float bv = bias ? bias[gc] : 0.f;
#pragma unroll
      for (int rg = 0; rg < 4; ++rg) {
        int grow = rbase + rg;
        float vv = acc[m][n][rg] + bv;
        if (EPI == EPI_GELU) {
          float x3 = vv * vv * vv;
          vv = 0.5f * vv * (1.f + tanhf(0.7978845608028654f * (vv + 0.044715f * x3)));
        }
        if (EPI == EPI_F32) {
          ((float*)outp)[(long)grow * Ndim + gc] = vv;
        } else if (EPI == EPI_VT) {
          // scatter into vT[b, h, dh, token]
          int bb = grow >> 12, tok = grow & 4095;
          int hh = gc >> 6, dd = gc & 63;
          ((u16*)outp)[((long)((bb * 16 + hh) * 64 + dd) << 12) + tok] = f2b(vv);
        } else {
          ((u16*)outp)[(long)grow * Ndim + gc] = f2b(vv);
        }
      }
    }
  }
}

// ---------------- fused XL attention, round-5 ----------------
// grid: (T/128, B*H), block 512 (8 waves x 16 q-rows each). Swapped-operand scores
// (lane q=l&15 owns one q-row), G/P share one per-wave LDS union (G consumed
// before P written; same-wave LDS ordering). All LDS stores stay in the
// short-family type system (u16x4) so TBAA cannot reorder them against the
// u16/s16x8 loads (round-4 NaN root cause). Qu/Qv pre-scaled into log2 domain,
// defer-rescale (THR=8), R rows clamped to [0,4095], 3 blocks/CU.
#define SCALE_LOG2 0.18033688011111793f  // 0.125 * log2(e)

__global__ __launch_bounds__(512, 6) void attn_fused(
    const u16* __restrict__ qg, const u16* __restrict__ kg, const u16* __restrict__ vTg,
    const u16* __restrict__ rg, const float* __restrict__ u, const float* __restrict__ vparam,
    const int* __restrict__ causal_p, u16* __restrict__ Og) {
  __shared__ __align__(16) u16 Ks[2][64 * 64];   // 16 KB
  __shared__ __align__(16) u16 Vs[2][64 * 64];   // 16 KB
  __shared__ __align__(16) u16 GPs[8][16 * 84];  // 21 KB: per-wave G(pitch84) then P(pitch72)

  const int bh = blockIdx.y, b = bh >> 4, h = bh & 15;
  const int i0 = (int)(gridDim.x - 1 - blockIdx.x) * 128;  // heavy blocks first
  const int t = threadIdx.x, w = t >> 6, l = t & 63;
  const int q = l & 15, g = l >> 4, lk = g * 8;
  const int causal = causal_p[0];

  const long kbase = ((long)b * 4096) * 1024 + h * 64;
  const long vbase = ((long)((b * 16 + h) * 64)) * 4096;

  // Q fragments (B-operand layout = row q, k-chunk g*8), u/v bias added and
  // PRE-SCALED by 0.125*log2(e) so scores come out of MFMA in exp2 domain.
  const int irow = i0 + 16 * w + q;
  const u16* qp = qg + ((long)(b * 2048 + irow)) * 1024 + h * 64;
  s16x8 qlo = *(const s16x8*)(qp + lk);
  s16x8 qhi = *(const s16x8*)(qp + 32 + lk);
  s16x8 qu0, qu1, qv0, qv1;
#pragma unroll
  for (int j = 0; j < 8; ++j) {
    float a0 = b2f((u16)qlo[j]), a1 = b2f((u16)qhi[j]);
    float uu0 = u[h * 64 + lk + j], vv0 = vparam[h * 64 + lk + j];
    float uu1 = u[h * 64 + 32 + lk + j], vv1 = vparam[h * 64 + 32 + lk + j];
    qu0[j] = (short)f2b((a0 + uu0) * SCALE_LOG2); qv0[j] = (short)f2b((a0 + vv0) * SCALE_LOG2);
    qu1[j] = (short)f2b((a1 + uu1) * SCALE_LOG2); qv1[j] = (short)f2b((a1 + vv1) * SCALE_LOG2);
  }

  float mrow = -3e38f, lrow = 0.f;
  f32x4 oacc[4];
#pragma unroll
  for (int n = 0; n < 4; ++n) oacc[n] = f32x4{0.f, 0.f, 0.f, 0.f};

  // stage K/V tile (512 threads: one 16B chunk each per tensor), swizzled source
  auto STAGE = [&](int j0s, int bufi) {
    int rrow = t >> 3, gch = (t & 7) ^ (rrow & 7);
    GLD_LDS16(kg + kbase + (long)(j0s + rrow) * 1024 + gch * 8, &Ks[bufi][t * 8]);
    GLD_LDS16(vTg + vbase + (long)rrow * 4096 + j0s + gch * 8, &Vs[bufi][t * 8]);
  };

  const int jmax = causal ? (2048 + i0 + 128) : 4096;
  const int nt = jmax >> 6;
  const int jlimit = 2048 + i0 + 16 * w + 15;  // last key any of this wave's rows needs
  STAGE(0, 0);
  int cur = 0;

  for (int ti = 0; ti < nt; ++ti) {
    const int j0 = ti << 6;
    asm volatile("s_waitcnt vmcnt(0)" ::: "memory");
    __syncthreads();
    if (ti + 1 < nt) STAGE((ti + 1) << 6, cur ^ 1);

    if (!causal || j0 <= jlimit) {
      // ---- R fragments (A-operand: band row dlo+tt*16+q, k-chunk g*8), clamped ----
      const int dlo = 2048 + i0 + 16 * w - j0 - 63;
      s16x8 rf0[5], rf1[5];
#pragma unroll
      for (int tt = 0; tt < 5; ++tt) {
        int d = dlo + tt * 16 + q; d = min(max(d, 0), 4095);
        const u16* rp = rg + ((long)d << 10) + h * 64;
        rf0[tt] = *(const s16x8*)(rp + lk);
        rf1[tt] = *(const s16x8*)(rp + 32 + lk);
      }

      // ---- AC^T = mfma(K, Qu): sv[n] reg r <-> key n*16+4g+r, col q ----
      f32x4 sv[4];
      __builtin_amdgcn_s_setprio(1);
#pragma unroll
      for (int n = 0; n < 4; ++n) {
        int r = n * 16 + q;
        s16x8 af0 = *(const s16x8*)&Ks[cur][r * 64 + ((g ^ (r & 7)) << 3)];
        s16x8 af1 = *(const s16x8*)&Ks[cur][r * 64 + (((g + 4) ^ (r & 7)) << 3)];
        f32x4 z = f32x4{0.f, 0.f, 0.f, 0.f};
        z = MFMA16(af0, qu0, z);
        z = MFMA16(af1, qu1, z);
        sv[n] = z;
      }
      // ---- G^T = mfma(R, Qv): band pos p = tt*16+4g+reg, col q -> G[q][p] (pitch 84) ----
#pragma unroll
      for (int tt = 0; tt < 5; ++tt) {
        f32x4 z = f32x4{0.f, 0.f, 0.f, 0.f};
        z = MFMA16(rf0[tt], qv0, z);
        z = MFMA16(rf1[tt], qv1, z);
        u16x4 pk = {f2b(z[0]), f2b(z[1]), f2b(z[2]), f2b(z[3])};
        *(u16x4*)&GPs[w][q * 84 + tt * 16 + 4 * g] = pk;  // 8B-aligned b64 write
      }
      __builtin_amdgcn_s_setprio(0);

      // ---- pass 1: scores (BD gather p = 63+q-j), in-lane max + 2 shfl ----
      const bool need_mask = (causal != 0) && (j0 + 63 > 2048 + i0 + 16 * w);
      float s[4][4];
      float mt = -3e38f;
#pragma unroll
      for (int n = 0; n < 4; ++n) {
#pragma unroll
        for (int r = 0; r < 4; ++r) {
          int j = n * 16 + 4 * g + r;
          float bd = b2f(GPs[w][q * 84 + 63 + q - j]);
          float scv = sv[n][r] + bd;  // already log2-domain (pre-scaled Q)
          if (need_mask && (j0 + j > 2048 + irow)) scv = -3e38f;
          s[n][r] = scv;
          mt = fmaxf(mt, scv);
        }
      }
      mt = fmaxf(mt, __shfl_xor(mt, 16));
      mt = fmaxf(mt, __shfl_xor(mt, 32));

      // ---- defer-rescale (T13): only rescale when some row max grew > THR ----
      if (!__all(mt <= mrow + 8.f)) {
        float mn = fmaxf(mrow, mt);
        float scl = __builtin_amdgcn_exp2f(mrow - mn);
        mrow = mn;
        lrow *= scl;
#pragma unroll
        for (int n = 0; n < 4; ++n) oacc[n] *= scl;
      }

      // ---- pass 2: exp2, pack P (pitch 72, same buffer; after all G reads) ----
      float rs = 0.f;
#pragma unroll
      for (int n = 0; n < 4; ++n) {
        float p0 = __builtin_amdgcn_exp2f(s[n][0] - mrow);
        float p1 = __builtin_amdgcn_exp2f(s[n][1] - mrow);
        float p2 = __builtin_amdgcn_exp2f(s[n][2] - mrow);
        float p3 = __builtin_amdgcn_exp2f(s[n][3] - mrow);
        rs += (p0 + p1) + (p2 + p3);
        u16x4 pk = {f2b(p0), f2b(p1), f2b(p2), f2b(p3)};
        *(u16x4*)&GPs[w][q * 72 + n * 16 + 4 * g] = pk;  // 8B-aligned b64 write
      }
      rs += __shfl_xor(rs, 16);
      rs += __shfl_xor(rs, 32);
      lrow += rs;

      // ---- PV swapped: O^T = mfma(V_asA, P_asB): rows d, col q ----
      s16x8 pb0 = *(const s16x8*)&GPs[w][q * 72 + lk];        // keys 0..31, chunk g
      s16x8 pb1 = *(const s16x8*)&GPs[w][q * 72 + 32 + lk];   // keys 32..63
      __builtin_amdgcn_s_setprio(1);
#pragma unroll
      for (int n = 0; n < 4; ++n) {
        int r = n * 16 + q;
        s16x8 va0 = *(const s16x8*)&Vs[cur][r * 64 + ((g ^ (r & 7)) << 3)];
        s16x8 va1 = *(const s16x8*)&Vs[cur][r * 64 + (((g + 4) ^ (r & 7)) << 3)];
        oacc[n] = MFMA16(va0, pb0, oacc[n]);
        oacc[n] = MFMA16(va1, pb1, oacc[n]);
      }
      __builtin_amdgcn_s_setprio(0);
    }
    cur ^= 1;
  }

  // ---- epilogue: lane holds O^T[d = n*16+4g+reg, q]; scale by 1/l (lane-local) ----
  const float linv = 1.f / lrow;
  const long obase = (long)(b * 2048 + irow) * 1024 + h * 64;
#pragma unroll
  for (int n = 0; n < 4; ++n) {
    u16x4 ov = {f2b(oacc[n][0] * linv), f2b(oacc[n][1] * linv),
                f2b(oacc[n][2] * linv), f2b(oacc[n][3] * linv)};
    *(u16x4*)&Og[obase + n * 16 + 4 * g] = ov;
  }
}

// ---------------- LayerNorm(a + resid)*g + be -> fp32 (+optional bf16) ----------------
template <int WRITE_BF16>
__global__ __launch_bounds__(256) void ln_res(const float* __restrict__ a,
                                              const float* __restrict__ resid,
                                              const float* __restrict__ g,
                                              const float* __restrict__ be,
                                              float* __restrict__ outf, u16* __restrict__ outb) {
  const int row = blockIdx.x;
  const int t = threadIdx.x;
  const long base = (long)row * 1024;
  float4 av = *(const float4*)&a[base + t * 4];
  float4 rv = *(const float4*)&resid[base + t * 4];
  float x0 = av.x + rv.x, x1 = av.y + rv.y, x2 = av.z + rv.z, x3 = av.w + rv.w;
  float s = x0 + x1 + x2 + x3;
  float q = x0 * x0 + x1 * x1 + x2 * x2 + x3 * x3;
#pragma unroll
  for (int d = 1; d < 64; d <<= 1) {
    s += __shfl_xor(s, d);
    q += __shfl_xor(q, d);
  }
  __shared__ float ss[4], sq[4];
  if ((t & 63) == 0) { ss[t >> 6] = s; sq[t >> 6] = q; }
  __syncthreads();
  s = ss[0] + ss[1] + ss[2] + ss[3];
  q = sq[0] + sq[1] + sq[2] + sq[3];
  float mu = s * (1.f / 1024.f);
  float var = q * (1.f / 1024.f) - mu * mu;
  float rstd = rsqrtf(var + 1e-5f);
  float4 gv = *(const float4*)&g[t * 4];
  float4 bv = *(const float4*)&be[t * 4];
  float y0 = (x0 - mu) * rstd * gv.x + bv.x;
  float y1 = (x1 - mu) * rstd * gv.y + bv.y;
  float y2 = (x2 - mu) * rstd * gv.z + bv.z;
  float y3 = (x3 - mu) * rstd * gv.w + bv.w;
  float4 ov = {y0, y1, y2, y3};
  *(float4*)&outf[base + t * 4] = ov;
  if (WRITE_BF16) {
    uint2 o;
    o.x = (unsigned)f2b(y0) | ((unsigned)f2b(y1) << 16);
    o.y = (unsigned)f2b(y2) | ((unsigned)f2b(y3) << 16);
    *(uint2*)&outb[base + t * 4] = o;
  }
}

// ---------------- launcher ----------------
extern "C" void kernel_launch(void* const* d_in, const int* in_sizes, int n_in, void* d_out,
                              int out_size, void* d_ws, size_t ws_size, hipStream_t stream) {
  const float* x = (const float*)d_in[0];
  const float* mem = (const float*)d_in[1];
  const float* Wq = (const float*)d_in[2];
  const float* bq = (const float*)d_in[3];
  const float* Wk = (const float*)d_in[4];
  const float* bk = (const float*)d_in[5];
  const float* Wv = (const float*)d_in[6];
  const float* bv = (const float*)d_in[7];
  const float* Wo = (const float*)d_in[8];
  const float* bo = (const float*)d_in[9];
  const float* Wr = (const float*)d_in[10];
  const float* u = (const float*)d_in[11];
  const float* vp = (const float*)d_in[12];
  const float* g1 = (const float*)d_in[13];
  const float* be1 = (const float*)d_in[14];
  const float* g2 = (const float*)d_in[15];
  const float* be2 = (const float*)d_in[16];
  const float* W1 = (const float*)d_in[17];
  const float* b1 = (const float*)d_in[18];
  const float* W2 = (const float*)d_in[19];
  const float* b2 = (const float*)d_in[20];
  const int* iscaus = (const int*)d_in[21];

  char* ws = (char*)d_ws;
  const size_t MB = 1024 * 1024;
  // layout (170 MiB total, with aliasing; lifetimes audited):
  u16* WqT = (u16*)(ws + 0 * MB);
  u16* WkT = (u16*)(ws + 2 * MB);
  u16* WvT = (u16*)(ws + 4 * MB);
  u16* WoT = (u16*)(ws + 6 * MB);
  u16* WrT = (u16*)(ws + 8 * MB);
  u16* W1T = (u16*)(ws + 10 * MB);
  u16* W2T = (u16*)(ws + 18 * MB);
  u16* cb = (u16*)(ws + 26 * MB);    // [B*4096,1024] bf16 (32MB); dead after k/v/q gemms
  float* proj = (float*)(ws + 26 * MB);  // aliases cb; h lives here after LN1
  u16* pe = (u16*)(ws + 58 * MB);    // 8MB; dead after r gemm
  u16* qb = (u16*)(ws + 66 * MB);    // 16MB
  u16* kb = (u16*)(ws + 82 * MB);    // 32MB
  u16* vT = (u16*)(ws + 114 * MB);   // 32MB
  u16* rb = (u16*)(ws + 146 * MB);   // 8MB
  u16* aO = (u16*)(ws + 154 * MB);   // 16MB; dead after proj gemm
  u16* hb = (u16*)(ws + 154 * MB);   // aliases aO
  u16* f1 = (u16*)(ws + 58 * MB);    // 64MB over pe+qb+kb(+8MB of vT) — all dead by then
  float* f2 = (float*)(ws + 122 * MB);  // 32MB over vT tail + rb — dead by then
  (void)ws_size; (void)in_sizes; (void)n_in; (void)out_size;

  // weights: cast + transpose to [N,K] bf16
  wt_cast_t<<<dim3(32, 32), 256, 0, stream>>>(Wq, WqT, 1024, 1024);
  wt_cast_t<<<dim3(32, 32), 256, 0, stream>>>(Wk, WkT, 1024, 1024);
  wt_cast_t<<<dim3(32, 32), 256, 0, stream>>>(Wv, WvT, 1024, 1024);
  wt_cast_t<<<dim3(32, 32), 256, 0, stream>>>(Wo, WoT, 1024, 1024);
  wt_cast_t<<<dim3(32, 32), 256, 0, stream>>>(Wr, WrT, 1024, 1024);
  wt_cast_t<<<dim3(128, 32), 256, 0, stream>>>(W1, W1T, 1024, 4096);
  wt_cast_t<<<dim3(32, 128), 256, 0, stream>>>(W2, W2T, 4096, 1024);

  build_cb<<<16384, 256, 0, stream>>>(x, mem, cb);
  pos_emb<<<4096, 256, 0, stream>>>(pe);

  // projections
  gemm_bt<EPI_BF16, 1><<<dim3(8, 64), 256, 0, stream>>>(cb, WqT, bq, qb, 1024, 1024);
  gemm_bt<EPI_BF16, 0><<<dim3(8, 128), 256, 0, stream>>>(cb, WkT, bk, kb, 1024, 1024);
  gemm_bt<EPI_VT, 0><<<dim3(8, 128), 256, 0, stream>>>(cb, WvT, bv, vT, 1024, 1024);
  gemm_bt<EPI_BF16, 0><<<dim3(8, 32), 256, 0, stream>>>(pe, WrT, nullptr, rb, 1024, 1024);

  // fused attention (8 waves, QBLK=128, 3 blocks/CU)
  attn_fused<<<dim3(16, 64), 512, 0, stream>>>(qb, kb, vT, rb, u, vp, iscaus, aO);

  // output projection + LN1
  gemm_bt<EPI_F32, 0><<<dim3(8, 64), 256, 0, stream>>>(aO, WoT, bo, proj, 1024, 1024);
  ln_res<1><<<8192, 256, 0, stream>>>(proj, x, g1, be1, proj, hb);

  // FFN + LN2
  gemm_bt<EPI_GELU, 0><<<dim3(32, 64), 256, 0, stream>>>(hb, W1T, b1, f1, 4096, 1024);
  gemm_bt<EPI_F32, 0><<<dim3(8, 64), 256, 0, stream>>>(f1, W2T, b2, f2, 1024, 4096);
  ln_res<0><<<8192, 256, 0, stream>>>(f2, proj, g2, be2, (float*)d_out, nullptr);
}

// Round 6
// 1011.241 us; speedup vs baseline: 2.3179x; 2.3179x over previous
//
#include <hip/hip_runtime.h>
#include <stdint.h>

// ---------------- common types / helpers ----------------
typedef unsigned short u16;
typedef short s16x8 __attribute__((ext_vector_type(8)));
typedef unsigned short u16x4 __attribute__((ext_vector_type(4)));
typedef float f32x4 __attribute__((ext_vector_type(4)));

#define DEV static __device__ __forceinline__

DEV u16 f2b(float f) {
  union { float f; unsigned u; } v; v.f = f;
  unsigned r = v.u + 0x7fffu + ((v.u >> 16) & 1u);
  return (u16)(r >> 16);
}
DEV float b2f(u16 b) {
  union { unsigned u; float f; } v; v.u = ((unsigned)b) << 16; return v.f;
}
DEV f32x4 MFMA16(s16x8 a, s16x8 b, f32x4 c) {
  return __builtin_amdgcn_mfma_f32_16x16x32_bf16(a, b, c, 0, 0, 0);
}
#define GLD_LDS16(gp, lp)                                                            \
  __builtin_amdgcn_global_load_lds((const __attribute__((address_space(1))) void*)(gp), \
                                   (__attribute__((address_space(3))) void*)(lp), 16, 0, 0)

// dims: B=4 T=2048 M=2048 K=4096 D=1024 H=16 DH=64 FFN=4096

// ---------------- weight cast + transpose: Wt[n,k] = bf16(W[k,n]) ----------------
__global__ __launch_bounds__(256) void wt_cast_t(const float* __restrict__ W,
                                                 u16* __restrict__ Wt, int Kd, int Nd) {
  __shared__ float tile[32][33];
  const int n0 = blockIdx.x * 32, k0 = blockIdx.y * 32;
  const int t = threadIdx.x;
#pragma unroll
  for (int p = 0; p < 4; ++p) {
    int idx = p * 256 + t; int r = idx >> 5, c = idx & 31;
    tile[r][c] = W[(long)(k0 + r) * Nd + n0 + c];
  }
  __syncthreads();
#pragma unroll
  for (int p = 0; p < 4; ++p) {
    int idx = p * 256 + t; int r = idx >> 5, c = idx & 31;
    Wt[(long)(n0 + r) * Kd + k0 + c] = f2b(tile[c][r]);
  }
}

// ---------------- cb = bf16(concat(mem, x)) : [B,4096,1024] ----------------
__global__ __launch_bounds__(256) void build_cb(const float* __restrict__ x,
                                                const float* __restrict__ mem,
                                                u16* __restrict__ cb) {
  long idx = (long)blockIdx.x * 256 + threadIdx.x;  // one per 4 elems
  long e4 = idx * 4;
  int b = (int)(e4 >> 22);
  long rem = e4 & ((1L << 22) - 1);
  int tok = (int)(rem >> 10);
  int d = (int)(rem & 1023);
  const float* src = (tok < 2048) ? &mem[((long)b * 2048 + tok) * 1024 + d]
                                  : &x[((long)b * 2048 + (tok - 2048)) * 1024 + d];
  float4 vv = *(const float4*)src;
  uint2 o;
  o.x = (unsigned)f2b(vv.x) | ((unsigned)f2b(vv.y) << 16);
  o.y = (unsigned)f2b(vv.z) | ((unsigned)f2b(vv.w) << 16);
  *(uint2*)&cb[e4] = o;
}

// ---------------- pe[d, e] distance-indexed sinusoid table (bf16) ----------------
__global__ __launch_bounds__(256) void pos_emb(u16* __restrict__ pe) {
  const int d = blockIdx.x;          // 0..4095 (relative distance)
  const int e0 = threadIdx.x * 4;
  u16 o[4];
#pragma unroll
  for (int i = 0; i < 4; ++i) {
    int e = e0 + i;
    int f = (e < 512) ? e : (e - 512);
    float invf = expf(-(float)f * (9.210340371976184f / 512.f));  // 10000^(-f/512)
    float ang = (float)d * invf;
    o[i] = f2b((e < 512) ? sinf(ang) : cosf(ang));
  }
  uint2 pk; pk.x = (unsigned)o[0] | ((unsigned)o[1] << 16);
  pk.y = (unsigned)o[2] | ((unsigned)o[3] << 16);
  *(uint2*)&pe[(long)d * 1024 + e0] = pk;
}

// ---------------- GEMM: C[M,N] = A[M,K](bf16) @ Bt[N,K](bf16)^T + bias ----------------
#define EPI_BF16 0
#define EPI_F32 1
#define EPI_GELU 2
#define EPI_VT 3

template <int EPI, int QMAP>
__global__ __launch_bounds__(256) void gemm_bt(const u16* __restrict__ A,
                                               const u16* __restrict__ Bt,
                                               const float* __restrict__ bias,
                                               void* __restrict__ outp, int Ndim, int Kdim) {
  __shared__ __align__(16) u16 As[128 * 32];
  __shared__ __align__(16) u16 Bs[128 * 32];
  const int col0 = blockIdx.x * 128;
  const int row0 = blockIdx.y * 128;
  const int t = threadIdx.x;
  const int w = t >> 6, l = t & 63;
  const int wr = (w >> 1) * 64, wc = (w & 1) * 64;
  const int lr = l & 15, lk = (l >> 4) * 8;
  f32x4 acc[4][4];
#pragma unroll
  for (int m = 0; m < 4; ++m)
#pragma unroll
    for (int n = 0; n < 4; ++n) acc[m][n] = f32x4{0.f, 0.f, 0.f, 0.f};

  for (int k0 = 0; k0 < Kdim; k0 += 32) {
#pragma unroll
    for (int it = 0; it < 2; ++it) {
      int c = it * 256 + t;
      int r = c >> 2, e = (c & 3) * 8;
      long ga = row0 + r;
      if (QMAP) ga = ((ga >> 11) << 12) + 2048 + (ga & 2047);  // q rows live in cb at b*4096+2048+i
      GLD_LDS16(A + ga * Kdim + k0 + e, &As[c * 8]);
      GLD_LDS16(Bt + (long)(col0 + r) * Kdim + k0 + e, &Bs[c * 8]);
    }
    __syncthreads();
    s16x8 af[4], bfv[4];
#pragma unroll
    for (int m = 0; m < 4; ++m) af[m] = *(const s16x8*)&As[(wr + m * 16 + lr) * 32 + lk];
#pragma unroll
    for (int n = 0; n < 4; ++n) bfv[n] = *(const s16x8*)&Bs[(wc + n * 16 + lr) * 32 + lk];
#pragma unroll
    for (int m = 0; m < 4; ++m)
#pragma unroll
      for (int n = 0; n < 4; ++n) acc[m][n] = MFMA16(af[m], bfv[n], acc[m][n]);
    __syncthreads();
  }

  const int lg = (l >> 4) * 4;
#pragma unroll
  for (int m = 0; m < 4; ++m) {
    int rbase = row0 + wr + m * 16 + lg;
#pragma unroll
    for (int n = 0; n < 4; ++n) {
      int gc = col0 + wc + n * 16 + lr;
      float bv = bias ? bias[gc] : 0.f;
#pragma unroll
      for (int rg = 0; rg < 4; ++rg) {
        int grow = rbase + rg;
        float vv = acc[m][n][rg] + bv;
        if (EPI == EPI_GELU) {
          float x3 = vv * vv * vv;
          vv = 0.5f * vv * (1.f + tanhf(0.7978845608028654f * (vv + 0.044715f * x3)));
        }
        if (EPI == EPI_F32) {
          ((float*)outp)[(long)grow * Ndim + gc] = vv;
        } else if (EPI == EPI_VT) {
          // scatter into vT[b, h, dh, token]
          int bb = grow >> 12, tok = grow & 4095;
          int hh = gc >> 6, dd = gc & 63;
          ((u16*)outp)[((long)((bb * 16 + hh) * 64 + dd) << 12) + tok] = f2b(vv);
        } else {
          ((u16*)outp)[(long)grow * Ndim + gc] = f2b(vv);
        }
      }
    }
  }
}

// ---------------- fused XL attention, round-6 ----------------
// grid: (B*H, T/128) — bh on x so consecutive dispatches (round-robin over XCDs)
// give each XCD a fixed bh subset (bh = xcd mod 8): all 16 q-tiles of a (b,h)
// land on ONE XCD -> K/V stream becomes L2-resident, shortening the per-tile
// vmcnt(0) drain (L2 ~200cy vs HBM ~900cy). Tiles processed heavy-first via
// i0 = (15 - blockIdx.y)*128. Block 512 = 8 waves x 16 q-rows.
// launch_bounds(512,4): round-5's (512,6) cap caused catastrophic scratch
// spill (VGPR 40 + 4.7GB scratch traffic); unforced allocation fit 64 VGPRs
// in round 3, and LDS (54272B) already permits 3 blocks/CU (<=54613B).
#define SCALE_LOG2 0.18033688011111793f  // 0.125 * log2(e)

__global__ __launch_bounds__(512, 4) void attn_fused(
    const u16* __restrict__ qg, const u16* __restrict__ kg, const u16* __restrict__ vTg,
    const u16* __restrict__ rg, const float* __restrict__ u, const float* __restrict__ vparam,
    const int* __restrict__ causal_p, u16* __restrict__ Og) {
  __shared__ __align__(16) u16 Ks[2][64 * 64];   // 16 KB
  __shared__ __align__(16) u16 Vs[2][64 * 64];   // 16 KB
  __shared__ __align__(16) u16 GPs[8][16 * 84];  // 21 KB: per-wave G(pitch84) then P(pitch72)

  const int bh = blockIdx.x, b = bh >> 4, h = bh & 15;
  const int i0 = (int)(gridDim.y - 1 - blockIdx.y) * 128;  // heavy tiles first
  const int t = threadIdx.x, w = t >> 6, l = t & 63;
  const int q = l & 15, g = l >> 4, lk = g * 8;
  const int causal = causal_p[0];

  const long kbase = ((long)b * 4096) * 1024 + h * 64;
  const long vbase = ((long)((b * 16 + h) * 64)) * 4096;

  // Q fragments (B-operand layout = row q, k-chunk g*8), u/v bias added and
  // PRE-SCALED by 0.125*log2(e) so scores come out of MFMA in exp2 domain.
  const int irow = i0 + 16 * w + q;
  const u16* qp = qg + ((long)(b * 2048 + irow)) * 1024 + h * 64;
  s16x8 qlo = *(const s16x8*)(qp + lk);
  s16x8 qhi = *(const s16x8*)(qp + 32 + lk);
  s16x8 qu0, qu1, qv0, qv1;
#pragma unroll
  for (int j = 0; j < 8; ++j) {
    float a0 = b2f((u16)qlo[j]), a1 = b2f((u16)qhi[j]);
    float uu0 = u[h * 64 + lk + j], vv0 = vparam[h * 64 + lk + j];
    float uu1 = u[h * 64 + 32 + lk + j], vv1 = vparam[h * 64 + 32 + lk + j];
    qu0[j] = (short)f2b((a0 + uu0) * SCALE_LOG2); qv0[j] = (short)f2b((a0 + vv0) * SCALE_LOG2);
    qu1[j] = (short)f2b((a1 + uu1) * SCALE_LOG2); qv1[j] = (short)f2b((a1 + vv1) * SCALE_LOG2);
  }

  float mrow = -3e38f, lrow = 0.f;
  f32x4 oacc[4];
#pragma unroll
  for (int n = 0; n < 4; ++n) oacc[n] = f32x4{0.f, 0.f, 0.f, 0.f};

  // stage K/V tile (512 threads: one 16B chunk each per tensor), swizzled source
  auto STAGE = [&](int j0s, int bufi) {
    int rrow = t >> 3, gch = (t & 7) ^ (rrow & 7);
    GLD_LDS16(kg + kbase + (long)(j0s + rrow) * 1024 + gch * 8, &Ks[bufi][t * 8]);
    GLD_LDS16(vTg + vbase + (long)rrow * 4096 + j0s + gch * 8, &Vs[bufi][t * 8]);
  };

  const int jmax = causal ? (2048 + i0 + 128) : 4096;
  const int nt = jmax >> 6;
  const int jlimit = 2048 + i0 + 16 * w + 15;  // last key any of this wave's rows needs
  STAGE(0, 0);
  int cur = 0;

  for (int ti = 0; ti < nt; ++ti) {
    const int j0 = ti << 6;
    asm volatile("s_waitcnt vmcnt(0)" ::: "memory");
    __syncthreads();
    if (ti + 1 < nt) STAGE((ti + 1) << 6, cur ^ 1);

    if (!causal || j0 <= jlimit) {
      // ---- R fragments (A-operand: band row dlo+tt*16+q, k-chunk g*8), clamped ----
      const int dlo = 2048 + i0 + 16 * w - j0 - 63;
      s16x8 rf0[5], rf1[5];
#pragma unroll
      for (int tt = 0; tt < 5; ++tt) {
        int d = dlo + tt * 16 + q; d = min(max(d, 0), 4095);
        const u16* rp = rg + ((long)d << 10) + h * 64;
        rf0[tt] = *(const s16x8*)(rp + lk);
        rf1[tt] = *(const s16x8*)(rp + 32 + lk);
      }

      // ---- AC^T = mfma(K, Qu): sv[n] reg r <-> key n*16+4g+r, col q ----
      f32x4 sv[4];
      __builtin_amdgcn_s_setprio(1);
#pragma unroll
      for (int n = 0; n < 4; ++n) {
        int r = n * 16 + q;
        s16x8 af0 = *(const s16x8*)&Ks[cur][r * 64 + ((g ^ (r & 7)) << 3)];
        s16x8 af1 = *(const s16x8*)&Ks[cur][r * 64 + (((g + 4) ^ (r & 7)) << 3)];
        f32x4 z = f32x4{0.f, 0.f, 0.f, 0.f};
        z = MFMA16(af0, qu0, z);
        z = MFMA16(af1, qu1, z);
        sv[n] = z;
      }
      // ---- G^T = mfma(R, Qv): band pos p = tt*16+4g+reg, col q -> G[q][p] (pitch 84) ----
#pragma unroll
      for (int tt = 0; tt < 5; ++tt) {
        f32x4 z = f32x4{0.f, 0.f, 0.f, 0.f};
        z = MFMA16(rf0[tt], qv0, z);
        z = MFMA16(rf1[tt], qv1, z);
        u16x4 pk = {f2b(z[0]), f2b(z[1]), f2b(z[2]), f2b(z[3])};
        *(u16x4*)&GPs[w][q * 84 + tt * 16 + 4 * g] = pk;  // 8B-aligned b64 write
      }
      __builtin_amdgcn_s_setprio(0);

      // ---- pass 1: scores (BD gather p = 63+q-j), in-lane max + 2 shfl ----
      const bool need_mask = (causal != 0) && (j0 + 63 > 2048 + i0 + 16 * w);
      float s[4][4];
      float mt = -3e38f;
#pragma unroll
      for (int n = 0; n < 4; ++n) {
#pragma unroll
        for (int r = 0; r < 4; ++r) {
          int j = n * 16 + 4 * g + r;
          float bd = b2f(GPs[w][q * 84 + 63 + q - j]);
          float scv = sv[n][r] + bd;  // already log2-domain (pre-scaled Q)
          if (need_mask && (j0 + j > 2048 + irow)) scv = -3e38f;
          s[n][r] = scv;
          mt = fmaxf(mt, scv);
        }
      }
      mt = fmaxf(mt, __shfl_xor(mt, 16));
      mt = fmaxf(mt, __shfl_xor(mt, 32));

      // ---- defer-rescale (T13): only rescale when some row max grew > THR ----
      if (!__all(mt <= mrow + 8.f)) {
        float mn = fmaxf(mrow, mt);
        float scl = __builtin_amdgcn_exp2f(mrow - mn);
        mrow = mn;
        lrow *= scl;
#pragma unroll
        for (int n = 0; n < 4; ++n) oacc[n] *= scl;
      }

      // ---- pass 2: exp2, pack P (pitch 72, same buffer; after all G reads) ----
      float rs = 0.f;
#pragma unroll
      for (int n = 0; n < 4; ++n) {
        float p0 = __builtin_amdgcn_exp2f(s[n][0] - mrow);
        float p1 = __builtin_amdgcn_exp2f(s[n][1] - mrow);
        float p2 = __builtin_amdgcn_exp2f(s[n][2] - mrow);
        float p3 = __builtin_amdgcn_exp2f(s[n][3] - mrow);
        rs += (p0 + p1) + (p2 + p3);
        u16x4 pk = {f2b(p0), f2b(p1), f2b(p2), f2b(p3)};
        *(u16x4*)&GPs[w][q * 72 + n * 16 + 4 * g] = pk;  // 8B-aligned b64 write
      }
      rs += __shfl_xor(rs, 16);
      rs += __shfl_xor(rs, 32);
      lrow += rs;

      // ---- PV swapped: O^T = mfma(V_asA, P_asB): rows d, col q ----
      s16x8 pb0 = *(const s16x8*)&GPs[w][q * 72 + lk];        // keys 0..31, chunk g
      s16x8 pb1 = *(const s16x8*)&GPs[w][q * 72 + 32 + lk];   // keys 32..63
      __builtin_amdgcn_s_setprio(1);
#pragma unroll
      for (int n = 0; n < 4; ++n) {
        int r = n * 16 + q;
        s16x8 va0 = *(const s16x8*)&Vs[cur][r * 64 + ((g ^ (r & 7)) << 3)];
        s16x8 va1 = *(const s16x8*)&Vs[cur][r * 64 + (((g + 4) ^ (r & 7)) << 3)];
        oacc[n] = MFMA16(va0, pb0, oacc[n]);
        oacc[n] = MFMA16(va1, pb1, oacc[n]);
      }
      __builtin_amdgcn_s_setprio(0);
    }
    cur ^= 1;
  }

  // ---- epilogue: lane holds O^T[d = n*16+4g+reg, q]; scale by 1/l (lane-local) ----
  const float linv = 1.f / lrow;
  const long obase = (long)(b * 2048 + irow) * 1024 + h * 64;
#pragma unroll
  for (int n = 0; n < 4; ++n) {
    u16x4 ov = {f2b(oacc[n][0] * linv), f2b(oacc[n][1] * linv),
                f2b(oacc[n][2] * linv), f2b(oacc[n][3] * linv)};
    *(u16x4*)&Og[obase + n * 16 + 4 * g] = ov;
  }
}

// ---------------- LayerNorm(a + resid)*g + be -> fp32 (+optional bf16) ----------------
template <int WRITE_BF16>
__global__ __launch_bounds__(256) void ln_res(const float* __restrict__ a,
                                              const float* __restrict__ resid,
                                              const float* __restrict__ g,
                                              const float* __restrict__ be,
                                              float* __restrict__ outf, u16* __restrict__ outb) {
  const int row = blockIdx.x;
  const int t = threadIdx.x;
  const long base = (long)row * 1024;
  float4 av = *(const float4*)&a[base + t * 4];
  float4 rv = *(const float4*)&resid[base + t * 4];
  float x0 = av.x + rv.x, x1 = av.y + rv.y, x2 = av.z + rv.z, x3 = av.w + rv.w;
  float s = x0 + x1 + x2 + x3;
  float q = x0 * x0 + x1 * x1 + x2 * x2 + x3 * x3;
#pragma unroll
  for (int d = 1; d < 64; d <<= 1) {
    s += __shfl_xor(s, d);
    q += __shfl_xor(q, d);
  }
  __shared__ float ss[4], sq[4];
  if ((t & 63) == 0) { ss[t >> 6] = s; sq[t >> 6] = q; }
  __syncthreads();
  s = ss[0] + ss[1] + ss[2] + ss[3];
  q = sq[0] + sq[1] + sq[2] + sq[3];
  float mu = s * (1.f / 1024.f);
  float var = q * (1.f / 1024.f) - mu * mu;
  float rstd = rsqrtf(var + 1e-5f);
  float4 gv = *(const float4*)&g[t * 4];
  float4 bv = *(const float4*)&be[t * 4];
  float y0 = (x0 - mu) * rstd * gv.x + bv.x;
  float y1 = (x1 - mu) * rstd * gv.y + bv.y;
  float y2 = (x2 - mu) * rstd * gv.z + bv.z;
  float y3 = (x3 - mu) * rstd * gv.w + bv.w;
  float4 ov = {y0, y1, y2, y3};
  *(float4*)&outf[base + t * 4] = ov;
  if (WRITE_BF16) {
    uint2 o;
    o.x = (unsigned)f2b(y0) | ((unsigned)f2b(y1) << 16);
    o.y = (unsigned)f2b(y2) | ((unsigned)f2b(y3) << 16);
    *(uint2*)&outb[base + t * 4] = o;
  }
}

// ---------------- launcher ----------------
extern "C" void kernel_launch(void* const* d_in, const int* in_sizes, int n_in, void* d_out,
                              int out_size, void* d_ws, size_t ws_size, hipStream_t stream) {
  const float* x = (const float*)d_in[0];
  const float* mem = (const float*)d_in[1];
  const float* Wq = (const float*)d_in[2];
  const float* bq = (const float*)d_in[3];
  const float* Wk = (const float*)d_in[4];
  const float* bk = (const float*)d_in[5];
  const float* Wv = (const float*)d_in[6];
  const float* bv = (const float*)d_in[7];
  const float* Wo = (const float*)d_in[8];
  const float* bo = (const float*)d_in[9];
  const float* Wr = (const float*)d_in[10];
  const float* u = (const float*)d_in[11];
  const float* vp = (const float*)d_in[12];
  const float* g1 = (const float*)d_in[13];
  const float* be1 = (const float*)d_in[14];
  const float* g2 = (const float*)d_in[15];
  const float* be2 = (const float*)d_in[16];
  const float* W1 = (const float*)d_in[17];
  const float* b1 = (const float*)d_in[18];
  const float* W2 = (const float*)d_in[19];
  const float* b2 = (const float*)d_in[20];
  const int* iscaus = (const int*)d_in[21];

  char* ws = (char*)d_ws;
  const size_t MB = 1024 * 1024;
  // layout (170 MiB total, with aliasing; lifetimes audited):
  u16* WqT = (u16*)(ws + 0 * MB);
  u16* WkT = (u16*)(ws + 2 * MB);
  u16* WvT = (u16*)(ws + 4 * MB);
  u16* WoT = (u16*)(ws + 6 * MB);
  u16* WrT = (u16*)(ws + 8 * MB);
  u16* W1T = (u16*)(ws + 10 * MB);
  u16* W2T = (u16*)(ws + 18 * MB);
  u16* cb = (u16*)(ws + 26 * MB);    // [B*4096,1024] bf16 (32MB); dead after k/v/q gemms
  float* proj = (float*)(ws + 26 * MB);  // aliases cb; h lives here after LN1
  u16* pe = (u16*)(ws + 58 * MB);    // 8MB; dead after r gemm
  u16* qb = (u16*)(ws + 66 * MB);    // 16MB
  u16* kb = (u16*)(ws + 82 * MB);    // 32MB
  u16* vT = (u16*)(ws + 114 * MB);   // 32MB
  u16* rb = (u16*)(ws + 146 * MB);   // 8MB
  u16* aO = (u16*)(ws + 154 * MB);   // 16MB; dead after proj gemm
  u16* hb = (u16*)(ws + 154 * MB);   // aliases aO
  u16* f1 = (u16*)(ws + 58 * MB);    // 64MB over pe+qb+kb(+8MB of vT) — all dead by then
  float* f2 = (float*)(ws + 122 * MB);  // 32MB over vT tail + rb — dead by then
  (void)ws_size; (void)in_sizes; (void)n_in; (void)out_size;

  // weights: cast + transpose to [N,K] bf16
  wt_cast_t<<<dim3(32, 32), 256, 0, stream>>>(Wq, WqT, 1024, 1024);
  wt_cast_t<<<dim3(32, 32), 256, 0, stream>>>(Wk, WkT, 1024, 1024);
  wt_cast_t<<<dim3(32, 32), 256, 0, stream>>>(Wv, WvT, 1024, 1024);
  wt_cast_t<<<dim3(32, 32), 256, 0, stream>>>(Wo, WoT, 1024, 1024);
  wt_cast_t<<<dim3(32, 32), 256, 0, stream>>>(Wr, WrT, 1024, 1024);
  wt_cast_t<<<dim3(128, 32), 256, 0, stream>>>(W1, W1T, 1024, 4096);
  wt_cast_t<<<dim3(32, 128), 256, 0, stream>>>(W2, W2T, 4096, 1024);

  build_cb<<<16384, 256, 0, stream>>>(x, mem, cb);
  pos_emb<<<4096, 256, 0, stream>>>(pe);

  // projections
  gemm_bt<EPI_BF16, 1><<<dim3(8, 64), 256, 0, stream>>>(cb, WqT, bq, qb, 1024, 1024);
  gemm_bt<EPI_BF16, 0><<<dim3(8, 128), 256, 0, stream>>>(cb, WkT, bk, kb, 1024, 1024);
  gemm_bt<EPI_VT, 0><<<dim3(8, 128), 256, 0, stream>>>(cb, WvT, bv, vT, 1024, 1024);
  gemm_bt<EPI_BF16, 0><<<dim3(8, 32), 256, 0, stream>>>(pe, WrT, nullptr, rb, 1024, 1024);

  // fused attention (8 waves, QBLK=128; bh on x for XCD L2 locality)
  attn_fused<<<dim3(64, 16), 512, 0, stream>>>(qb, kb, vT, rb, u, vp, iscaus, aO);

  // output projection + LN1
  gemm_bt<EPI_F32, 0><<<dim3(8, 64), 256, 0, stream>>>(aO, WoT, bo, proj, 1024, 1024);
  ln_res<1><<<8192, 256, 0, stream>>>(proj, x, g1, be1, proj, hb);

  // FFN + LN2
  gemm_bt<EPI_GELU, 0><<<dim3(32, 64), 256, 0, stream>>>(hb, W1T, b1, f1, 4096, 1024);
  gemm_bt<EPI_F32, 0><<<dim3(8, 64), 256, 0, stream>>>(f1, W2T, b2, f2, 1024, 4096);
  ln_res<0><<<8192, 256, 0, stream>>>(f2, proj, g2, be2, (float*)d_out, nullptr);
}